// Round 1
// baseline (413.498 us; speedup 1.0000x reference)
//
#include <hip/hip_runtime.h>
#include <hip/hip_fp16.h>

// MDLSTM 64x64 grid, B=32, I=64, O=128.
// Decomposition:
//   K1: lut[p] = cell index for diagonal-packed order p
//   K2: gx[b][g][o][p] (f16) = x @ {wf0,wf1,wi,wo,wc}   (bias added later)
//   K3: recurrence, one wave per (b,o), lane j = column j, anti-diagonal sweep,
//       left-neighbor via __shfl_up. No inter-wave communication at all.
// Workspace: gx = 5*32*128*4096 half = 160 MiB, lut = 16 KiB after it.

#define NCELL 4096
#define GX_ELEMS ((size_t)32 * 5 * 128 * 4096)

__device__ __forceinline__ float sigmoidf_(float x) {
    return __fdividef(1.f, 1.f + __expf(-x));
}
__device__ __forceinline__ float tanhf_(float x) {
    float e = __expf(-2.f * fabsf(x));
    float t = __fdividef(1.f - e, 1.f + e);
    return copysignf(t, x);
}
// offset of diagonal d in packed order (D1=D2=64)
__device__ __forceinline__ int diag_off(int d) {
    return (d < 64) ? ((d * (d + 1)) >> 1) : (4096 - (((127 - d) * (128 - d)) >> 1));
}

__global__ __launch_bounds__(256) void lut_kernel(int* __restrict__ lut) {
    int t = blockIdx.x * 256 + threadIdx.x;   // 0..4095 = i*64+j
    int i = t >> 6, j = t & 63;
    int d = i + j;
    int jmin = (d > 63) ? (d - 63) : 0;
    lut[diag_off(d) + j - jmin] = t;
}

typedef __attribute__((ext_vector_type(8))) _Float16 half8;

// fp32 tiled GEMM: tile 128p x 128o, K=64 resident. grid (32 p-tiles, 32 b, 5 gates)
__global__ __launch_bounds__(256) void gemm_kernel(
    const float* __restrict__ x, const float* __restrict__ wf,
    const float* __restrict__ wi, const float* __restrict__ wo,
    const float* __restrict__ wc, const int* __restrict__ lut,
    __half* __restrict__ gx)
{
    __shared__ float As[64][132];  // As[k][p]  (A transposed)
    __shared__ float Bs[64][132];  // Bs[k][o]
    const int t  = threadIdx.x;
    const int p0 = blockIdx.x * 128;
    const int b  = blockIdx.y;
    const int g  = blockIdx.z;
    const float* W = (g == 0) ? wf
                   : (g == 1) ? (wf + 64 * 128)
                   : (g == 2) ? wi
                   : (g == 3) ? wo : wc;
    // load B tile: 64k x 128o floats (= whole W_g)
#pragma unroll
    for (int q = 0; q < 8; ++q) {
        int f = t + q * 256;               // 0..2047 float4 units
        int k = f >> 5, o4 = (f & 31) * 4;
        *(float4*)(&Bs[k][o4]) = *(const float4*)(W + k * 128 + o4);
    }
    // load A tile transposed: rows p0+r, k=0..63
#pragma unroll
    for (int q = 0; q < 8; ++q) {
        int f = t + q * 256;
        int r = f >> 4, c4 = (f & 15) * 4;
        int cell = lut[p0 + r];
        float4 v = *(const float4*)(x + ((size_t)cell * 32 + b) * 64 + c4);
        As[c4 + 0][r] = v.x; As[c4 + 1][r] = v.y;
        As[c4 + 2][r] = v.z; As[c4 + 3][r] = v.w;
    }
    __syncthreads();

    const int tr = t & 15;   // p direction (8 outputs)
    const int tc = t >> 4;   // o direction (8 outputs)
    float acc[8][8] = {};
#pragma unroll 8
    for (int k = 0; k < 64; ++k) {
        float4 a0 = *(const float4*)(&As[k][tr * 8]);
        float4 a1 = *(const float4*)(&As[k][tr * 8 + 4]);
        float4 b0 = *(const float4*)(&Bs[k][tc * 8]);
        float4 b1 = *(const float4*)(&Bs[k][tc * 8 + 4]);
        float av[8] = {a0.x, a0.y, a0.z, a0.w, a1.x, a1.y, a1.z, a1.w};
        float bv[8] = {b0.x, b0.y, b0.z, b0.w, b1.x, b1.y, b1.z, b1.w};
#pragma unroll
        for (int u = 0; u < 8; ++u)
#pragma unroll
            for (int v = 0; v < 8; ++v)
                acc[u][v] += av[u] * bv[v];
    }
    // store: gx[((b*5+g)*128 + o)*4096 + p] as f16, 16B per (v)
    const size_t base = (size_t)(b * 5 + g) * 128 * 4096;
#pragma unroll
    for (int v = 0; v < 8; ++v) {
        int o = tc * 8 + v;
        half8 tmp;
#pragma unroll
        for (int u = 0; u < 8; ++u) tmp[u] = (_Float16)acc[u][v];
        *(half8*)(gx + base + (size_t)o * 4096 + p0 + tr * 8) = tmp;
    }
}

// recurrence: wave w = (b,o); lane j = column j; 127 anti-diagonal steps
__global__ __launch_bounds__(256) void recur_kernel(
    const __half* __restrict__ gx,
    const float* __restrict__ uf, const float* __restrict__ biasf,
    const float* __restrict__ ui, const float* __restrict__ biasi,
    const float* __restrict__ uo, const float* __restrict__ biaso,
    const float* __restrict__ uc, const float* __restrict__ biasc,
    float* __restrict__ out)
{
    const int j = threadIdx.x & 63;
    const int w = blockIdx.x * 4 + (threadIdx.x >> 6);  // 0..4095
    const int b = w >> 7, o = w & 127;

    // per-wave (o-dependent) scalars — identical across lanes, broadcast loads
    const float sbf0 = biasf[o],        sbf1 = biasf[128 + o];
    const float uf00 = uf[o],           uf01 = uf[128 + o];
    const float uf10 = uf[256 + o],     uf11 = uf[384 + o];
    const float sui0 = ui[o],           sui1 = ui[128 + o],  sbi = biasi[o];
    const float suo0 = uo[o],           suo1 = uo[128 + o],  sbo = biaso[o];
    const float suc0 = uc[o],           suc1 = uc[128 + o],  sbc = biasc[o];

    const __half* g0 = gx + ((size_t)(b * 5 + 0) * 128 + o) * 4096;
    const __half* g1 = gx + ((size_t)(b * 5 + 1) * 128 + o) * 4096;
    const __half* g2 = gx + ((size_t)(b * 5 + 2) * 128 + o) * 4096;
    const __half* g3 = gx + ((size_t)(b * 5 + 3) * 128 + o) * 4096;
    const __half* g4 = gx + ((size_t)(b * 5 + 4) * 128 + o) * 4096;

    auto calc_p = [&](int d) -> int {
        int jmin = (d > 63) ? (d - 63) : 0;
        int p = diag_off(d) + j - jmin;
        return min(max(p, 0), 4095);   // clamp for off-diagonal (inactive) lanes
    };

    float s_prev = 0.f, h_prev = 0.f;
    int p = calc_p(0);
    float c0 = __half2float(g0[p]);
    float c1 = __half2float(g1[p]);
    float c2 = __half2float(g2[p]);
    float c3 = __half2float(g3[p]);
    float c4 = __half2float(g4[p]);

    for (int d = 0; d < 127; ++d) {
        // prefetch next diagonal's preactivations (addresses independent of state)
        int pn = calc_p(min(d + 1, 126));
        float n0 = __half2float(g0[pn]);
        float n1 = __half2float(g1[pn]);
        float n2 = __half2float(g2[pn]);
        float n3 = __half2float(g3[pn]);
        float n4 = __half2float(g4[pn]);

        float s_left = __shfl_up(s_prev, 1, 64);
        float h_left = __shfl_up(h_prev, 1, 64);
        if (j == 0) { s_left = 0.f; h_left = 0.f; }

        int i = d - j;
        bool active = (i >= 0) && (i < 64);

        // h_prev/s_prev hold this lane's previous row = up-neighbor (0 if i==0)
        float f0 = sigmoidf_(sbf0 + c0 + h_prev * uf00 + h_left * uf01);
        float f1 = sigmoidf_(sbf1 + c1 + h_prev * uf10 + h_left * uf11);
        float ig = sigmoidf_(sbi  + c2 + h_prev * sui0 + h_left * sui1);
        float og = sigmoidf_(sbo  + c3 + h_prev * suo0 + h_left * suo1);
        float cg = sigmoidf_(sbc  + c4 + h_prev * suc0 + h_left * suc1);

        float s = ig * cg + f0 * s_prev + f1 * s_left;
        float h = og * tanhf_(s);

        if (active) out[((size_t)(i * 64 + j) * 32 + b) * 128 + o] = s;

        s_prev = active ? s : 0.f;
        h_prev = active ? h : 0.f;
        c0 = n0; c1 = n1; c2 = n2; c3 = n3; c4 = n4;
    }
}

extern "C" void kernel_launch(void* const* d_in, const int* in_sizes, int n_in,
                              void* d_out, int out_size, void* d_ws, size_t ws_size,
                              hipStream_t stream) {
    const float* x     = (const float*)d_in[0];
    const float* wf    = (const float*)d_in[1];
    const float* uf    = (const float*)d_in[2];
    const float* biasf = (const float*)d_in[3];
    const float* wi    = (const float*)d_in[4];
    const float* ui    = (const float*)d_in[5];
    const float* biasi = (const float*)d_in[6];
    const float* wo    = (const float*)d_in[7];
    const float* uo    = (const float*)d_in[8];
    const float* biaso = (const float*)d_in[9];
    const float* wc    = (const float*)d_in[10];
    const float* uc    = (const float*)d_in[11];
    const float* biasc = (const float*)d_in[12];
    float* out = (float*)d_out;

    // ws layout: gx (f16, 160 MiB) | lut (16 KiB).  Needs ~160.02 MiB.
    __half* gx = (__half*)d_ws;
    int* lut = (int*)((char*)d_ws + GX_ELEMS * sizeof(__half));

    lut_kernel<<<16, 256, 0, stream>>>(lut);
    gemm_kernel<<<dim3(32, 32, 5), 256, 0, stream>>>(x, wf, wi, wo, wc, lut, gx);
    recur_kernel<<<1024, 256, 0, stream>>>(gx, uf, biasf, ui, biasi,
                                           uo, biaso, uc, biasc, out);
}

// Round 2
// 341.975 us; speedup vs baseline: 1.2091x; 1.2091x over previous
//
#include <hip/hip_runtime.h>
#include <hip/hip_fp16.h>

// MDLSTM 64x64 grid, B=32, I=64, O=128.
//   K1: lut[p] = cell index (i*64+j) for diagonal-packed order p
//   K2 (MFMA f16): gx[b][g][o][p] (f16) = -(x @ W_g + bias_g)   [negation+bias folded]
//   K3: recurrence, one wave per (b,o), lane j = column j, anti-diagonal sweep.
//       All per-step address math is incremental scalar adds; sigmoid via rcp(1+expf).
// Workspace: gx = 5*32*128*4096 half = 160 MiB, lut = 16 KiB after it.

#define GX_ELEMS ((size_t)32 * 5 * 128 * 4096)

typedef __attribute__((ext_vector_type(8))) _Float16 half8;
typedef __attribute__((ext_vector_type(4))) float f32x4;

__device__ __forceinline__ int diag_off(int d) {
    return (d < 64) ? ((d * (d + 1)) >> 1) : (4096 - (((127 - d) * (128 - d)) >> 1));
}

__global__ __launch_bounds__(256) void lut_kernel(int* __restrict__ lut) {
    int t = blockIdx.x * 256 + threadIdx.x;   // 0..4095 = i*64+j
    int i = t >> 6, j = t & 63;
    int d = i + j;
    int jmin = (d > 63) ? (d - 63) : 0;
    lut[diag_off(d) + j - jmin] = t;
}

// MFMA GEMM: tile 128p x 128o, K=64 resident. grid (32 p-tiles, 32 b, 5 gates).
// Stores gx = -(x@W + bias) as f16, layout [b][g][o][p] (p contiguous).
__global__ __launch_bounds__(256) void gemm_kernel(
    const float* __restrict__ x, const float* __restrict__ wf,
    const float* __restrict__ wi, const float* __restrict__ wo,
    const float* __restrict__ wc,
    const float* __restrict__ biasf, const float* __restrict__ biasi,
    const float* __restrict__ biaso, const float* __restrict__ biasc,
    const int* __restrict__ lut, __half* __restrict__ gx)
{
    __shared__ _Float16 As[128][72];    // [p][k], pitch 72 halves (2-way free banks)
    __shared__ _Float16 Bs[128][72];    // [o][k] = -W transposed
    __shared__ _Float16 Cs[128][136];   // [o][p] staging for coalesced store

    const int t  = threadIdx.x;
    const int p0 = blockIdx.x * 128;
    const int b  = blockIdx.y;
    const int g  = blockIdx.z;
    const float* W    = (g == 0) ? wf : (g == 1) ? (wf + 8192)
                      : (g == 2) ? wi : (g == 3) ? wo : wc;
    const float* bias = (g == 0) ? biasf : (g == 1) ? (biasf + 128)
                      : (g == 2) ? biasi : (g == 3) ? biaso : biasc;

    // --- stage A: x rows (via lut) -> f16, As[p][k]
    {
        int r = t >> 1, k0 = (t & 1) * 32;
        int cell = lut[p0 + r];
        const float* xr = x + ((size_t)cell * 32 + b) * 64 + k0;
#pragma unroll
        for (int it = 0; it < 4; ++it) {
            float4 v0 = *(const float4*)(xr + it * 8);
            float4 v1 = *(const float4*)(xr + it * 8 + 4);
            half8 h;
            h[0] = (_Float16)v0.x; h[1] = (_Float16)v0.y;
            h[2] = (_Float16)v0.z; h[3] = (_Float16)v0.w;
            h[4] = (_Float16)v1.x; h[5] = (_Float16)v1.y;
            h[6] = (_Float16)v1.z; h[7] = (_Float16)v1.w;
            *(half8*)&As[r][k0 + it * 8] = h;
        }
    }
    // --- stage B: Bs[o][k] = -W[k][o] as f16 (transpose)
    {
        int o = t >> 1, k0 = (t & 1) * 32;
#pragma unroll
        for (int it = 0; it < 4; ++it) {
            half8 h;
#pragma unroll
            for (int q = 0; q < 8; ++q)
                h[q] = (_Float16)(-W[(k0 + it * 8 + q) * 128 + o]);
            *(half8*)&Bs[o][k0 + it * 8] = h;
        }
    }
    __syncthreads();

    const int lane = t & 63;
    const int wv   = __builtin_amdgcn_readfirstlane(t >> 6);  // wave id 0..3
    const int m    = lane & 15;
    const int quad = lane >> 4;

    float sb0 = -bias[wv * 32 + m];
    float sb1 = -bias[wv * 32 + 16 + m];

    f32x4 acc[8][2] = {};
#pragma unroll
    for (int kh = 0; kh < 2; ++kh) {
        half8 bf0 = *(half8*)&Bs[wv * 32 + m][kh * 32 + quad * 8];
        half8 bf1 = *(half8*)&Bs[wv * 32 + 16 + m][kh * 32 + quad * 8];
#pragma unroll
        for (int pf = 0; pf < 8; ++pf) {
            half8 af = *(half8*)&As[pf * 16 + m][kh * 32 + quad * 8];
            acc[pf][0] = __builtin_amdgcn_mfma_f32_16x16x32_f16(af, bf0, acc[pf][0], 0, 0, 0);
            acc[pf][1] = __builtin_amdgcn_mfma_f32_16x16x32_f16(af, bf1, acc[pf][1], 0, 0, 0);
        }
    }
    // --- C frags -> Cs[o][p] (add scaled bias). frag: col(o)=lane&15, row(p)=quad*4+reg
#pragma unroll
    for (int pf = 0; pf < 8; ++pf) {
#pragma unroll
        for (int of = 0; of < 2; ++of) {
            int o  = wv * 32 + of * 16 + m;
            int pc = pf * 16 + quad * 4;
            float sb = of ? sb1 : sb0;
            __half2 lo = __floats2half2_rn(acc[pf][of][0] + sb, acc[pf][of][1] + sb);
            __half2 hi = __floats2half2_rn(acc[pf][of][2] + sb, acc[pf][of][3] + sb);
            uint2 pk;
            pk.x = *(unsigned*)&lo;
            pk.y = *(unsigned*)&hi;
            *(uint2*)&Cs[o][pc] = pk;
        }
    }
    __syncthreads();
    // --- coalesced store: 128 o-rows x 256 B
    __half* gbase = gx + ((size_t)(b * 5 + g) * 128) * 4096 + p0;
#pragma unroll
    for (int it = 0; it < 8; ++it) {
        int o = it * 16 + (t >> 4);
        int c = (t & 15) * 8;
        half8 v = *(half8*)&Cs[o][c];
        *(half8*)(gbase + (size_t)o * 4096 + c) = v;
    }
}

// recurrence: wave w = (b,o); lane j = column j; 127 anti-diagonal steps.
// gx already holds -(xW+bias); u weights pre-negated -> gate = rcp(1+exp(z)).
__global__ __launch_bounds__(256) void recur_kernel(
    const __half* __restrict__ gx,
    const float* __restrict__ uf, const float* __restrict__ ui,
    const float* __restrict__ uo, const float* __restrict__ uc,
    float* __restrict__ out)
{
    const int lane = threadIdx.x & 63;
    const int w = __builtin_amdgcn_readfirstlane(blockIdx.x * 4 + (threadIdx.x >> 6));
    const int b = w >> 7, o = w & 127;

    const float nf00 = -uf[o],       nf01 = -uf[128 + o];
    const float nf10 = -uf[256 + o], nf11 = -uf[384 + o];
    const float ni0 = -ui[o], ni1 = -ui[128 + o];
    const float no0 = -uo[o], no1 = -uo[128 + o];
    const float nc0 = -uc[o], nc1 = -uc[128 + o];

    const char* base = (const char*)(gx + ((size_t)(b * 5) * 128 + o) * 4096);
    const int SL  = 128 * 4096 * 2;       // gate stride in bytes
    const int l2  = lane * 2;
    const int zm  = (lane == 0) ? 0 : -1; // left-neighbor zero mask
    const int bpi = (lane - 1) * 4;       // bpermute byte index

    int svb = 0;                          // uniform byte offset of current load-diagonal
    float c0,c1,c2,c3,c4, n0,n1,n2,n3,n4;

#define LD5(v0_,v1_,v2_,v3_,v4_)                                   \
    { const char* p_ = base + svb;                                 \
      v0_ = (float)*(const _Float16*)(p_ + l2);                    \
      v1_ = (float)*(const _Float16*)(p_ + SL + l2);               \
      v2_ = (float)*(const _Float16*)(p_ + 2 * SL + l2);           \
      v3_ = (float)*(const _Float16*)(p_ + 3 * SL + l2);           \
      v4_ = (float)*(const _Float16*)(p_ + 4 * SL + l2); }

    LD5(c0,c1,c2,c3,c4); svb += 2;        // diag 0 loaded; delta(0)=1
    LD5(n0,n1,n2,n3,n4); svb += 4;        // diag 1 loaded; delta(1)=2

    float s_prev = 0.f, h_prev = 0.f;
    int oidx = lane * 4096 - lane * 262144 + b * 128 + o;  // d=0 store index

    for (int d = 0; d < 127; ++d) {
        // prefetch diag d+2 (self-clamps at 126 via delta=0)
        float t0,t1,t2,t3,t4;
        LD5(t0,t1,t2,t3,t4);
        int del = min(d + 3, 124 - d); del = max(del, 0);
        svb += del * 2;

        int slb = __builtin_amdgcn_ds_bpermute(bpi, __float_as_int(s_prev)) & zm;
        int hlb = __builtin_amdgcn_ds_bpermute(bpi, __float_as_int(h_prev)) & zm;
        float sl = __int_as_float(slb), hl = __int_as_float(hlb);

        float zf0 = fmaf(h_prev, nf00, fmaf(hl, nf01, c0));
        float zf1 = fmaf(h_prev, nf10, fmaf(hl, nf11, c1));
        float zi  = fmaf(h_prev, ni0,  fmaf(hl, ni1,  c2));
        float zo  = fmaf(h_prev, no0,  fmaf(hl, no1,  c3));
        float zc  = fmaf(h_prev, nc0,  fmaf(hl, nc1,  c4));
        float f0 = __builtin_amdgcn_rcpf(1.f + __expf(zf0));
        float f1 = __builtin_amdgcn_rcpf(1.f + __expf(zf1));
        float ig = __builtin_amdgcn_rcpf(1.f + __expf(zi));
        float og = __builtin_amdgcn_rcpf(1.f + __expf(zo));
        float cg = __builtin_amdgcn_rcpf(1.f + __expf(zc));

        float s  = fmaf(ig, cg, fmaf(f0, s_prev, f1 * sl));
        float e2 = __expf(s + s);
        float th = fmaf(-2.f, __builtin_amdgcn_rcpf(1.f + e2), 1.f);
        float h  = og * th;

        bool act = (unsigned)(d - lane) < 64u;   // i = d-j in [0,64)
        s_prev = act ? s : 0.f;
        h_prev = act ? h : 0.f;
        if (act) out[oidx] = s;
        oidx += 262144;

        c0 = n0; c1 = n1; c2 = n2; c3 = n3; c4 = n4;
        n0 = t0; n1 = t1; n2 = t2; n3 = t3; n4 = t4;
    }
#undef LD5
}

extern "C" void kernel_launch(void* const* d_in, const int* in_sizes, int n_in,
                              void* d_out, int out_size, void* d_ws, size_t ws_size,
                              hipStream_t stream) {
    const float* x     = (const float*)d_in[0];
    const float* wf    = (const float*)d_in[1];
    const float* uf    = (const float*)d_in[2];
    const float* biasf = (const float*)d_in[3];
    const float* wi    = (const float*)d_in[4];
    const float* ui    = (const float*)d_in[5];
    const float* biasi = (const float*)d_in[6];
    const float* wo    = (const float*)d_in[7];
    const float* uo    = (const float*)d_in[8];
    const float* biaso = (const float*)d_in[9];
    const float* wc    = (const float*)d_in[10];
    const float* uc    = (const float*)d_in[11];
    const float* biasc = (const float*)d_in[12];
    float* out = (float*)d_out;

    __half* gx = (__half*)d_ws;
    int* lut = (int*)((char*)d_ws + GX_ELEMS * sizeof(__half));

    lut_kernel<<<16, 256, 0, stream>>>(lut);
    gemm_kernel<<<dim3(32, 32, 5), 256, 0, stream>>>(
        x, wf, wi, wo, wc, biasf, biasi, biaso, biasc, lut, gx);
    recur_kernel<<<1024, 256, 0, stream>>>(gx, uf, ui, uo, uc, out);
}

// Round 3
// 248.010 us; speedup vs baseline: 1.6673x; 1.3789x over previous
//
#include <hip/hip_runtime.h>
#include <hip/hip_fp16.h>

// MDLSTM 64x64 grid, B=32, I=64, O=128.
//   K1 lut:   lut[p] = cell index (i*64+j) for diagonal-packed order p
//   K2 prep:  wt[g][o][k] (f16) = -W_g[k][o]  (negated, transposed, once)
//   K3 gemm:  gx[b][g][o][p] (f16) = -(x @ W_g + bias_g); A staged once per
//             (p-tile,b), gate loop reuses it (x read 1x, not 5x)
//   K4 recur: one wave per w=(b,o), lane j = column j, anti-diagonal sweep.
//             s stored f16 COALESCED into the dead g=0 plane of gx (slot was
//             consumed by the same lane 2 iterations earlier -> in-place safe).
//   K5 transpose: gx g0 plane [w][p] f16 -> out [cell][w] f32 via LDS tile.
// Workspace: gx 160 MiB | lut 16 KiB | wt 80 KiB.

#define GX_ELEMS ((size_t)32 * 5 * 128 * 4096)

typedef __attribute__((ext_vector_type(8))) _Float16 half8;
typedef __attribute__((ext_vector_type(4))) float f32x4;

__device__ __forceinline__ int diag_off(int d) {
    return (d < 64) ? ((d * (d + 1)) >> 1) : (4096 - (((127 - d) * (128 - d)) >> 1));
}

__global__ __launch_bounds__(256) void lut_kernel(int* __restrict__ lut) {
    int t = blockIdx.x * 256 + threadIdx.x;   // 0..4095 = i*64+j
    int i = t >> 6, j = t & 63;
    int d = i + j;
    int jmin = (d > 63) ? (d - 63) : 0;
    lut[diag_off(d) + j - jmin] = t;
}

// wt[g][o][k] = -(W_g[k][o]) as f16
__global__ __launch_bounds__(256) void prep_w(
    const float* __restrict__ wf, const float* __restrict__ wi,
    const float* __restrict__ wo, const float* __restrict__ wc,
    _Float16* __restrict__ wt)
{
    const int g = blockIdx.x;
    const float* W = (g == 0) ? wf : (g == 1) ? (wf + 8192)
                   : (g == 2) ? wi : (g == 3) ? wo : wc;
    const int t = threadIdx.x;
    const int o = t >> 1, k0 = (t & 1) * 32;
    _Float16 buf[32];
#pragma unroll
    for (int k = 0; k < 32; ++k) buf[k] = (_Float16)(-W[(k0 + k) * 128 + o]);
    _Float16* dst = wt + ((size_t)g * 128 + o) * 64 + k0;
#pragma unroll
    for (int q = 0; q < 4; ++q) *(half8*)(dst + q * 8) = *(half8*)(buf + q * 8);
}

// MFMA GEMM: tile 128p x 128o, K=64 resident, 5 gates per block (A reused).
__global__ __launch_bounds__(256) void gemm_kernel(
    const float* __restrict__ x, const _Float16* __restrict__ wt,
    const float* __restrict__ biasf, const float* __restrict__ biasi,
    const float* __restrict__ biaso, const float* __restrict__ biasc,
    const int* __restrict__ lut, __half* __restrict__ gx)
{
    __shared__ _Float16 As[128][72];     // [p][k]
    __shared__ _Float16 BC[128 * 136];   // union: Bs [o][72] / Cs [o][136]

    const int t  = threadIdx.x;
    const int p0 = blockIdx.x * 128;
    const int b  = blockIdx.y;

    // --- stage A once: x rows (via lut) -> f16, As[p][k]
    {
        int r = t >> 1, k0 = (t & 1) * 32;
        int cell = lut[p0 + r];
        const float* xr = x + ((size_t)cell * 32 + b) * 64 + k0;
#pragma unroll
        for (int it = 0; it < 4; ++it) {
            float4 v0 = *(const float4*)(xr + it * 8);
            float4 v1 = *(const float4*)(xr + it * 8 + 4);
            half8 h;
            h[0] = (_Float16)v0.x; h[1] = (_Float16)v0.y;
            h[2] = (_Float16)v0.z; h[3] = (_Float16)v0.w;
            h[4] = (_Float16)v1.x; h[5] = (_Float16)v1.y;
            h[6] = (_Float16)v1.z; h[7] = (_Float16)v1.w;
            *(half8*)&As[r][k0 + it * 8] = h;
        }
    }

    const int lane = t & 63;
    const int wv   = __builtin_amdgcn_readfirstlane(t >> 6);
    const int m    = lane & 15;
    const int quad = lane >> 4;

    for (int g = 0; g < 5; ++g) {
        const float* bias = (g == 0) ? biasf : (g == 1) ? (biasf + 128)
                          : (g == 2) ? biasi : (g == 3) ? biaso : biasc;
        __syncthreads();   // As ready (g=0) / previous gate's store done
        // stage Bs[o][72] from wt (coalesced f16 copy)
        {
            const _Float16* wg = wt + (size_t)g * 8192;
#pragma unroll
            for (int q = 0; q < 4; ++q) {
                int f = t * 4 + q;
                int o = f >> 3, c = (f & 7) * 8;
                *(half8*)&BC[o * 72 + c] = *(const half8*)(wg + o * 64 + c);
            }
        }
        __syncthreads();
        half8 bf0[2], bf1[2];
#pragma unroll
        for (int kh = 0; kh < 2; ++kh) {
            bf0[kh] = *(half8*)&BC[(wv * 32 + m) * 72 + kh * 32 + quad * 8];
            bf1[kh] = *(half8*)&BC[(wv * 32 + 16 + m) * 72 + kh * 32 + quad * 8];
        }
        __syncthreads();   // b-frags in regs; BC free for Cs
        f32x4 acc[8][2] = {};
#pragma unroll
        for (int kh = 0; kh < 2; ++kh) {
#pragma unroll
            for (int pf = 0; pf < 8; ++pf) {
                half8 af = *(half8*)&As[pf * 16 + m][kh * 32 + quad * 8];
                acc[pf][0] = __builtin_amdgcn_mfma_f32_16x16x32_f16(af, bf0[kh], acc[pf][0], 0, 0, 0);
                acc[pf][1] = __builtin_amdgcn_mfma_f32_16x16x32_f16(af, bf1[kh], acc[pf][1], 0, 0, 0);
            }
        }
        // C frags (col(o)=lane&15, row(p)=quad*4+reg) -> Cs[o][136]
        float sb0 = -bias[wv * 32 + m];
        float sb1 = -bias[wv * 32 + 16 + m];
#pragma unroll
        for (int pf = 0; pf < 8; ++pf) {
#pragma unroll
            for (int of = 0; of < 2; ++of) {
                int o  = wv * 32 + of * 16 + m;
                int pc = pf * 16 + quad * 4;
                float sb = of ? sb1 : sb0;
                __half2 lo = __floats2half2_rn(acc[pf][of][0] + sb, acc[pf][of][1] + sb);
                __half2 hi = __floats2half2_rn(acc[pf][of][2] + sb, acc[pf][of][3] + sb);
                uint2 pk;
                pk.x = *(unsigned*)&lo;
                pk.y = *(unsigned*)&hi;
                *(uint2*)&BC[o * 136 + pc] = pk;
            }
        }
        __syncthreads();
        // coalesced store: 128 o-rows x 256 B
        __half* gbase = gx + ((size_t)(b * 5 + g) * 128) * 4096 + p0;
#pragma unroll
        for (int it = 0; it < 8; ++it) {
            int o = it * 16 + (t >> 4);
            int c = (t & 15) * 8;
            *(half8*)(gbase + (size_t)o * 4096 + c) = *(half8*)&BC[o * 136 + c];
        }
    }
}

// recurrence: wave w = (b,o); lane j = column j; 127 anti-diagonal steps.
// gx holds -(xW+bias); u pre-negated -> gate = rcp(1+exp(z)).
// s stored f16 in-place into the (already-consumed) g=0 plane, coalesced.
__global__ __launch_bounds__(256) void recur_kernel(
    __half* gx,
    const float* __restrict__ uf, const float* __restrict__ ui,
    const float* __restrict__ uo, const float* __restrict__ uc)
{
    const int lane = threadIdx.x & 63;
    const int w = __builtin_amdgcn_readfirstlane(blockIdx.x * 4 + (threadIdx.x >> 6));
    const int b = w >> 7, o = w & 127;

    const float nf00 = -uf[o],       nf01 = -uf[128 + o];
    const float nf10 = -uf[256 + o], nf11 = -uf[384 + o];
    const float ni0 = -ui[o], ni1 = -ui[128 + o];
    const float no0 = -uo[o], no1 = -uo[128 + o];
    const float nc0 = -uc[o], nc1 = -uc[128 + o];

    char* base = (char*)(gx + ((size_t)(b * 5) * 128 + o) * 4096);
    const int SL  = 128 * 4096 * 2;       // gate stride in bytes
    const int l2  = lane * 2;
    const int zm  = (lane == 0) ? 0 : -1;
    const int bpi = (lane - 1) * 4;

    int svb = 0;   // byte offset of prefetch diagonal (uniform)
    int sob = 0;   // byte offset of store diagonal (uniform)
    float c0,c1,c2,c3,c4, n0,n1,n2,n3,n4;

#define LD5(v0_,v1_,v2_,v3_,v4_)                                   \
    { const char* p_ = base + svb;                                 \
      v0_ = (float)*(const _Float16*)(p_ + l2);                    \
      v1_ = (float)*(const _Float16*)(p_ + SL + l2);               \
      v2_ = (float)*(const _Float16*)(p_ + 2 * SL + l2);           \
      v3_ = (float)*(const _Float16*)(p_ + 3 * SL + l2);           \
      v4_ = (float)*(const _Float16*)(p_ + 4 * SL + l2); }

    LD5(c0,c1,c2,c3,c4); svb += 2;        // diag 0; delta(0)=1
    LD5(n0,n1,n2,n3,n4); svb += 4;        // diag 1; delta(1)=2

    float s_prev = 0.f, h_prev = 0.f;

    for (int d = 0; d < 127; ++d) {
        // prefetch diag d+2 (delta clamps to 0 at the end)
        float t0,t1,t2,t3,t4;
        LD5(t0,t1,t2,t3,t4);
        int del = min(d + 3, 124 - d); del = max(del, 0);
        svb += del * 2;

        int slb = __builtin_amdgcn_ds_bpermute(bpi, __float_as_int(s_prev)) & zm;
        int hlb = __builtin_amdgcn_ds_bpermute(bpi, __float_as_int(h_prev)) & zm;
        float sl = __int_as_float(slb), hl = __int_as_float(hlb);

        float zf0 = fmaf(h_prev, nf00, fmaf(hl, nf01, c0));
        float zf1 = fmaf(h_prev, nf10, fmaf(hl, nf11, c1));
        float zi  = fmaf(h_prev, ni0,  fmaf(hl, ni1,  c2));
        float zo  = fmaf(h_prev, no0,  fmaf(hl, no1,  c3));
        float zc  = fmaf(h_prev, nc0,  fmaf(hl, nc1,  c4));
        float f0 = __builtin_amdgcn_rcpf(1.f + __expf(zf0));
        float f1 = __builtin_amdgcn_rcpf(1.f + __expf(zf1));
        float ig = __builtin_amdgcn_rcpf(1.f + __expf(zi));
        float og = __builtin_amdgcn_rcpf(1.f + __expf(zo));
        float cg = __builtin_amdgcn_rcpf(1.f + __expf(zc));

        float s  = fmaf(ig, cg, fmaf(f0, s_prev, f1 * sl));
        float e2 = __expf(s + s);
        float th = fmaf(-2.f, __builtin_amdgcn_rcpf(1.f + e2), 1.f);
        float h  = og * th;

        bool act = (unsigned)(d - lane) < 64u;   // i = d-j in [0,64)
        // coalesced f16 store into dead g0 slot (consumed 2 iters ago)
        if (act) *(_Float16*)(base + sob + l2) = (_Float16)s;
        sob += min(d + 1, 126 - d) * 2;

        s_prev = act ? s : 0.f;
        h_prev = act ? h : 0.f;
        c0 = n0; c1 = n1; c2 = n2; c3 = n3; c4 = n4;
        n0 = t0; n1 = t1; n2 = t2; n3 = t3; n4 = t4;
    }
#undef LD5
}

// gx g0 plane [w][p] f16 -> out[cell][w] f32.  Tile: 64 p x 256 w.
__global__ __launch_bounds__(256) void transpose_kernel(
    const __half* __restrict__ gx, const int* __restrict__ lut,
    float* __restrict__ out)
{
    __shared__ _Float16 T[256][80];
    const int t  = threadIdx.x;
    const int p0 = blockIdx.x * 64;
    const int w0 = blockIdx.y * 256;
#pragma unroll
    for (int it = 0; it < 8; ++it) {
        int wl = it * 32 + (t >> 3), pl = (t & 7) * 8;
        int w = w0 + wl;
        int row = (w >> 7) * 640 + (w & 127);   // gx row for (b,g=0,o)
        *(half8*)&T[wl][pl] =
            *(const half8*)((const _Float16*)gx + (size_t)row * 4096 + p0 + pl);
    }
    __syncthreads();
    float* ob = out + w0 + t;
#pragma unroll 4
    for (int p = 0; p < 64; ++p) {
        int cell = lut[p0 + p];                 // block-uniform -> scalar load
        ob[(size_t)cell * 4096] = (float)T[t][p];
    }
}

extern "C" void kernel_launch(void* const* d_in, const int* in_sizes, int n_in,
                              void* d_out, int out_size, void* d_ws, size_t ws_size,
                              hipStream_t stream) {
    const float* x     = (const float*)d_in[0];
    const float* wf    = (const float*)d_in[1];
    const float* uf    = (const float*)d_in[2];
    const float* biasf = (const float*)d_in[3];
    const float* wi    = (const float*)d_in[4];
    const float* ui    = (const float*)d_in[5];
    const float* biasi = (const float*)d_in[6];
    const float* wo    = (const float*)d_in[7];
    const float* uo    = (const float*)d_in[8];
    const float* biaso = (const float*)d_in[9];
    const float* wc    = (const float*)d_in[10];
    const float* uc    = (const float*)d_in[11];
    const float* biasc = (const float*)d_in[12];
    float* out = (float*)d_out;

    __half*   gx  = (__half*)d_ws;
    int*      lut = (int*)((char*)d_ws + GX_ELEMS * sizeof(__half));
    _Float16* wt  = (_Float16*)((char*)lut + 16384);

    lut_kernel<<<16, 256, 0, stream>>>(lut);
    prep_w<<<5, 256, 0, stream>>>(wf, wi, wo, wc, wt);
    gemm_kernel<<<dim3(32, 32), 256, 0, stream>>>(
        x, wt, biasf, biasi, biaso, biasc, lut, gx);
    recur_kernel<<<1024, 256, 0, stream>>>(gx, uf, ui, uo, uc);
    transpose_kernel<<<dim3(64, 16), 256, 0, stream>>>(gx, lut, out);
}

// Round 5
// 240.511 us; speedup vs baseline: 1.7192x; 1.0312x over previous
//
#include <hip/hip_runtime.h>
#include <hip/hip_fp16.h>

// MDLSTM 64x64 grid, B=32, I=64, O=128.
//   K1 lut:   lut[p] = cell index (i*64+j) for diagonal-packed order p
//   K2 prep:  wt[g][o][k] (f16) = -W_g[k][o] * log2(e)
//   K3 gemm:  pair-interleaved preactivations, gx~ = -(x@W+b)*log2e:
//               plane01[w][p] : dword = (f0,f1) f16 pair
//               plane23[w][p] : dword = (i,o)  f16 pair
//               plane4 [w][p] : f16   = c
//             One LDS tile (A only), B-frags straight from L2-hot wt,
//             one __syncthreads, direct dwordx4 frag stores.
//   K4 recur: one wave per w=(b,o), lane j = column j, anti-diagonal sweep.
//             3 loads/step via scalar-advanced pointers; gates = rcp(1+exp2(z~)).
//             s stored f16 into dead plane4 slots (consumed 2 steps earlier).
//   K5 transpose: plane4 [w][p] f16 -> out [cell][w] f32.
// Workspace: planes 64+64+32 = 160 MiB | lut 16 KiB | wt 80 KiB.

#define P23_OFF  ((size_t)64 << 20)
#define P4_OFF   ((size_t)128 << 20)
#define GX_BYTES ((size_t)160 << 20)
#define LOG2E    1.4426950408889634f

typedef __attribute__((ext_vector_type(8))) _Float16 half8;
typedef __attribute__((ext_vector_type(2))) __fp16 fp16x2;
typedef __attribute__((ext_vector_type(4))) float f32x4;

__device__ __forceinline__ unsigned pkrtz(float a, float b) {
    union { fp16x2 h; unsigned u; } c;
    c.h = __builtin_amdgcn_cvt_pkrtz(a, b);
    return c.u;
}

__device__ __forceinline__ int diag_off(int d) {
    return (d < 64) ? ((d * (d + 1)) >> 1) : (4096 - (((127 - d) * (128 - d)) >> 1));
}

__global__ __launch_bounds__(256) void lut_kernel(int* __restrict__ lut) {
    int t = blockIdx.x * 256 + threadIdx.x;   // 0..4095 = i*64+j
    int i = t >> 6, j = t & 63;
    int d = i + j;
    int jmin = (d > 63) ? (d - 63) : 0;
    lut[diag_off(d) + j - jmin] = t;
}

// wt[g][o][k] = -(W_g[k][o]) * log2e  as f16
__global__ __launch_bounds__(256) void prep_w(
    const float* __restrict__ wf, const float* __restrict__ wi,
    const float* __restrict__ wo, const float* __restrict__ wc,
    _Float16* __restrict__ wt)
{
    const int g = blockIdx.x;
    const float* W = (g == 0) ? wf : (g == 1) ? (wf + 8192)
                   : (g == 2) ? wi : (g == 3) ? wo : wc;
    const int t = threadIdx.x;
    const int o = t >> 1, k0 = (t & 1) * 32;
    _Float16 buf[32];
#pragma unroll
    for (int k = 0; k < 32; ++k)
        buf[k] = (_Float16)(-W[(k0 + k) * 128 + o] * LOG2E);
    _Float16* dst = wt + ((size_t)g * 128 + o) * 64 + k0;
#pragma unroll
    for (int q = 0; q < 4; ++q) *(half8*)(dst + q * 8) = *(half8*)(buf + q * 8);
}

// MFMA GEMM: tile 128p x 128o, K=64. grid (32 p-tiles, 32 b).
__global__ __launch_bounds__(256, 2) void gemm_kernel(
    const float* __restrict__ x, const _Float16* __restrict__ wt,
    const float* __restrict__ biasf, const float* __restrict__ biasi,
    const float* __restrict__ biaso, const float* __restrict__ biasc,
    const int* __restrict__ lut, char* __restrict__ gx)
{
    __shared__ _Float16 As[128][72];     // [p][k]
    const int t  = threadIdx.x;
    const int p0 = blockIdx.x * 128;
    const int b  = blockIdx.y;

    // stage A: x rows (via lut) -> f16, As[p][k]
    {
        int r = t >> 1, k0 = (t & 1) * 32;
        int cell = lut[p0 + r];
        const float* xr = x + ((size_t)cell * 32 + b) * 64 + k0;
#pragma unroll
        for (int it = 0; it < 4; ++it) {
            float4 v0 = *(const float4*)(xr + it * 8);
            float4 v1 = *(const float4*)(xr + it * 8 + 4);
            half8 h;
            h[0] = (_Float16)v0.x; h[1] = (_Float16)v0.y;
            h[2] = (_Float16)v0.z; h[3] = (_Float16)v0.w;
            h[4] = (_Float16)v1.x; h[5] = (_Float16)v1.y;
            h[6] = (_Float16)v1.z; h[7] = (_Float16)v1.w;
            *(half8*)&As[r][k0 + it * 8] = h;
        }
    }
    __syncthreads();

    const int lane = t & 63;
    const int wv   = __builtin_amdgcn_readfirstlane(t >> 6);
    const int m    = lane & 15;
    const int quad = lane >> 4;
    const int o0   = wv * 32 + m;       // of=0 column
    const int o1   = o0 + 16;           // of=1 column
    const size_t row0 = (size_t)(b * 128 + o0) * 4096;
    const size_t row1 = (size_t)(b * 128 + o1) * 4096;
    const int pq = p0 + quad * 4;

    // -------- pair phase: gates (ga, gb) -> packed dword plane --------
    auto pair_phase = [&](const _Float16* wga, const _Float16* wgb,
                          const float* bA, const float* bB, char* plane) {
        half8 ba0[2], ba1[2], bb0[2], bb1[2];
#pragma unroll
        for (int kh = 0; kh < 2; ++kh) {
            ba0[kh] = *(const half8*)(wga + o0 * 64 + kh * 32 + quad * 8);
            ba1[kh] = *(const half8*)(wga + o1 * 64 + kh * 32 + quad * 8);
            bb0[kh] = *(const half8*)(wgb + o0 * 64 + kh * 32 + quad * 8);
            bb1[kh] = *(const half8*)(wgb + o1 * 64 + kh * 32 + quad * 8);
        }
        f32x4 aA[8][2] = {}, aB[8][2] = {};
#pragma unroll
        for (int pf = 0; pf < 8; ++pf) {
            half8 af0 = *(const half8*)&As[pf * 16 + m][quad * 8];
            half8 af1 = *(const half8*)&As[pf * 16 + m][32 + quad * 8];
            aA[pf][0] = __builtin_amdgcn_mfma_f32_16x16x32_f16(af0, ba0[0], aA[pf][0], 0, 0, 0);
            aA[pf][0] = __builtin_amdgcn_mfma_f32_16x16x32_f16(af1, ba0[1], aA[pf][0], 0, 0, 0);
            aA[pf][1] = __builtin_amdgcn_mfma_f32_16x16x32_f16(af0, ba1[0], aA[pf][1], 0, 0, 0);
            aA[pf][1] = __builtin_amdgcn_mfma_f32_16x16x32_f16(af1, ba1[1], aA[pf][1], 0, 0, 0);
            aB[pf][0] = __builtin_amdgcn_mfma_f32_16x16x32_f16(af0, bb0[0], aB[pf][0], 0, 0, 0);
            aB[pf][0] = __builtin_amdgcn_mfma_f32_16x16x32_f16(af1, bb0[1], aB[pf][0], 0, 0, 0);
            aB[pf][1] = __builtin_amdgcn_mfma_f32_16x16x32_f16(af0, bb1[0], aB[pf][1], 0, 0, 0);
            aB[pf][1] = __builtin_amdgcn_mfma_f32_16x16x32_f16(af1, bb1[1], aB[pf][1], 0, 0, 0);
        }
        float sA0 = -bA[o0] * LOG2E, sA1 = -bA[o1] * LOG2E;
        float sB0 = -bB[o0] * LOG2E, sB1 = -bB[o1] * LOG2E;
#pragma unroll
        for (int pf = 0; pf < 8; ++pf) {
#pragma unroll
            for (int of = 0; of < 2; ++of) {
                float sa = of ? sA1 : sA0, sb = of ? sB1 : sB0;
                f32x4 va = aA[pf][of], vb = aB[pf][of];
                uint4 st;
                st.x = pkrtz(va[0] + sa, vb[0] + sb);
                st.y = pkrtz(va[1] + sa, vb[1] + sb);
                st.z = pkrtz(va[2] + sa, vb[2] + sb);
                st.w = pkrtz(va[3] + sa, vb[3] + sb);
                size_t row = of ? row1 : row0;
                *(uint4*)(plane + (row + pq + pf * 16) * 4) = st;
            }
        }
    };
    pair_phase(wt,            wt + 8192,     biasf, biasf + 128, gx);
    pair_phase(wt + 2 * 8192, wt + 3 * 8192, biasi, biaso,       gx + P23_OFF);

    // -------- single phase: gate c -> f16 plane4 --------
    {
        const _Float16* wg = wt + 4 * 8192;
        half8 b0[2], b1[2];
#pragma unroll
        for (int kh = 0; kh < 2; ++kh) {
            b0[kh] = *(const half8*)(wg + o0 * 64 + kh * 32 + quad * 8);
            b1[kh] = *(const half8*)(wg + o1 * 64 + kh * 32 + quad * 8);
        }
        f32x4 ac[8][2] = {};
#pragma unroll
        for (int pf = 0; pf < 8; ++pf) {
            half8 af0 = *(const half8*)&As[pf * 16 + m][quad * 8];
            half8 af1 = *(const half8*)&As[pf * 16 + m][32 + quad * 8];
            ac[pf][0] = __builtin_amdgcn_mfma_f32_16x16x32_f16(af0, b0[0], ac[pf][0], 0, 0, 0);
            ac[pf][0] = __builtin_amdgcn_mfma_f32_16x16x32_f16(af1, b0[1], ac[pf][0], 0, 0, 0);
            ac[pf][1] = __builtin_amdgcn_mfma_f32_16x16x32_f16(af0, b1[0], ac[pf][1], 0, 0, 0);
            ac[pf][1] = __builtin_amdgcn_mfma_f32_16x16x32_f16(af1, b1[1], ac[pf][1], 0, 0, 0);
        }
        float s0 = -biasc[o0] * LOG2E, s1 = -biasc[o1] * LOG2E;
        char* plane = gx + P4_OFF;
#pragma unroll
        for (int pf = 0; pf < 8; ++pf) {
#pragma unroll
            for (int of = 0; of < 2; ++of) {
                float sb = of ? s1 : s0;
                f32x4 v = ac[pf][of];
                uint2 st;
                st.x = pkrtz(v[0] + sb, v[1] + sb);
                st.y = pkrtz(v[2] + sb, v[3] + sb);
                size_t row = of ? row1 : row0;
                *(uint2*)(plane + (row + pq + pf * 16) * 2) = st;
            }
        }
    }
}

// recurrence: wave w = (b,o); lane j = column j; 127 anti-diagonal steps.
// planes hold z~ = -(xW+b)*log2e; u pre-scaled -> gate = rcp(1+exp2(z~)).
__global__ __launch_bounds__(256) void recur_kernel(
    char* __restrict__ gx,
    const float* __restrict__ uf, const float* __restrict__ ui,
    const float* __restrict__ uo, const float* __restrict__ uc)
{
    const int lane = threadIdx.x & 63;
    const int w = __builtin_amdgcn_readfirstlane(blockIdx.x * 4 + (threadIdx.x >> 6));
    const int o = w & 127;

    const float nf00 = -uf[o] * LOG2E,       nf01 = -uf[128 + o] * LOG2E;
    const float nf10 = -uf[256 + o] * LOG2E, nf11 = -uf[384 + o] * LOG2E;
    const float ni0 = -ui[o] * LOG2E, ni1 = -ui[128 + o] * LOG2E;
    const float no0 = -uo[o] * LOG2E, no1 = -uo[128 + o] * LOG2E;
    const float nc0 = -uc[o] * LOG2E, nc1 = -uc[128 + o] * LOG2E;

    // scalar-advanced base pointers (saddr codegen), fixed per-lane offsets
    const char* pc01 = gx + (size_t)w * 16384;
    const char* pc23 = gx + P23_OFF + (size_t)w * 16384;
    const char* pc4  = gx + P4_OFF + (size_t)w * 8192;
    char*       ps4  = gx + P4_OFF + (size_t)w * 8192;
    const int l4 = lane * 4, l2 = lane * 2;

    const int zm  = (lane == 0) ? 0 : -1;
    const int bpi = (lane - 1) * 4;

    float c0,c1,c2,c3,c4, n0,n1,n2,n3,n4;

#define LD3(v0_,v1_,v2_,v3_,v4_) { \
    __half2 h01 = *(const __half2*)(pc01 + l4); \
    __half2 h23 = *(const __half2*)(pc23 + l4); \
    _Float16 h4 = *(const _Float16*)(pc4 + l2); \
    v0_ = __low2float(h01); v1_ = __high2float(h01); \
    v2_ = __low2float(h23); v3_ = __high2float(h23); \
    v4_ = (float)h4; }

    LD3(c0,c1,c2,c3,c4); pc01 += 4;  pc23 += 4;  pc4 += 2;   // -> diag 1
    LD3(n0,n1,n2,n3,n4); pc01 += 8;  pc23 += 8;  pc4 += 4;   // -> diag 2

    float s_prev = 0.f, h_prev = 0.f;

    for (int d = 0; d < 127; ++d) {
        float t0,t1,t2,t3,t4;
        LD3(t0,t1,t2,t3,t4);                    // prefetch diag d+2
        int del = min(d + 3, 124 - d); del = max(del, 0);
        pc01 += del * 4; pc23 += del * 4; pc4 += del * 2;

        int slb = __builtin_amdgcn_ds_bpermute(bpi, __float_as_int(s_prev)) & zm;
        int hlb = __builtin_amdgcn_ds_bpermute(bpi, __float_as_int(h_prev)) & zm;
        float sl = __int_as_float(slb), hl = __int_as_float(hlb);

        float zf0 = fmaf(h_prev, nf00, fmaf(hl, nf01, c0));
        float zf1 = fmaf(h_prev, nf10, fmaf(hl, nf11, c1));
        float zi  = fmaf(h_prev, ni0,  fmaf(hl, ni1,  c2));
        float zo  = fmaf(h_prev, no0,  fmaf(hl, no1,  c3));
        float zc  = fmaf(h_prev, nc0,  fmaf(hl, nc1,  c4));
        float f0 = __builtin_amdgcn_rcpf(1.f + __builtin_amdgcn_exp2f(zf0));
        float f1 = __builtin_amdgcn_rcpf(1.f + __builtin_amdgcn_exp2f(zf1));
        float ig = __builtin_amdgcn_rcpf(1.f + __builtin_amdgcn_exp2f(zi));
        float og = __builtin_amdgcn_rcpf(1.f + __builtin_amdgcn_exp2f(zo));
        float cg = __builtin_amdgcn_rcpf(1.f + __builtin_amdgcn_exp2f(zc));

        float s  = fmaf(ig, cg, fmaf(f0, s_prev, f1 * sl));
        float e2 = __builtin_amdgcn_exp2f(s * (2.f * LOG2E));
        float th = fmaf(-2.f, __builtin_amdgcn_rcpf(1.f + e2), 1.f);
        float h  = og * th;

        bool act = (unsigned)(d - lane) < 64u;   // i = d-j in [0,64)
        if (act) *(_Float16*)(ps4 + l2) = (_Float16)s;   // dead slot, coalesced
        ps4 += min(d + 1, 126 - d) * 2;

        s_prev = act ? s : 0.f;
        h_prev = act ? h : 0.f;
        c0 = n0; c1 = n1; c2 = n2; c3 = n3; c4 = n4;
        n0 = t0; n1 = t1; n2 = t2; n3 = t3; n4 = t4;
    }
#undef LD3
}

// plane4 [w][p] f16 -> out[cell][w] f32.  Tile: 64 p x 256 w.
__global__ __launch_bounds__(256) void transpose_kernel(
    const char* __restrict__ gx, const int* __restrict__ lut,
    float* __restrict__ out)
{
    __shared__ _Float16 T[256][80];
    const _Float16* p4 = (const _Float16*)(gx + P4_OFF);
    const int t  = threadIdx.x;
    const int p0 = blockIdx.x * 64;
    const int w0 = blockIdx.y * 256;
#pragma unroll
    for (int it = 0; it < 8; ++it) {
        int wl = it * 32 + (t >> 3), pl = (t & 7) * 8;
        *(half8*)&T[wl][pl] =
            *(const half8*)(p4 + (size_t)(w0 + wl) * 4096 + p0 + pl);
    }
    __syncthreads();
    float* ob = out + w0 + t;
#pragma unroll 4
    for (int p = 0; p < 64; ++p) {
        int cell = lut[p0 + p];                 // block-uniform -> scalar load
        ob[(size_t)cell * 4096] = (float)T[t][p];
    }
}

extern "C" void kernel_launch(void* const* d_in, const int* in_sizes, int n_in,
                              void* d_out, int out_size, void* d_ws, size_t ws_size,
                              hipStream_t stream) {
    const float* x     = (const float*)d_in[0];
    const float* wf    = (const float*)d_in[1];
    const float* uf    = (const float*)d_in[2];
    const float* biasf = (const float*)d_in[3];
    const float* wi    = (const float*)d_in[4];
    const float* ui    = (const float*)d_in[5];
    const float* biasi = (const float*)d_in[6];
    const float* wo    = (const float*)d_in[7];
    const float* uo    = (const float*)d_in[8];
    const float* biaso = (const float*)d_in[9];
    const float* wc    = (const float*)d_in[10];
    const float* uc    = (const float*)d_in[11];
    const float* biasc = (const float*)d_in[12];
    float* out = (float*)d_out;

    char*     gx  = (char*)d_ws;
    int*      lut = (int*)(gx + GX_BYTES);
    _Float16* wt  = (_Float16*)((char*)lut + 16384);

    lut_kernel<<<16, 256, 0, stream>>>(lut);
    prep_w<<<5, 256, 0, stream>>>(wf, wi, wo, wc, wt);
    gemm_kernel<<<dim3(32, 32), 256, 0, stream>>>(
        x, wt, biasf, biasi, biaso, biasc, lut, gx);
    recur_kernel<<<1024, 256, 0, stream>>>(gx, uf, ui, uo, uc);
    transpose_kernel<<<dim3(64, 16), 256, 0, stream>>>(gx, lut, out);
}